// Round 11
// baseline (164.330 us; speedup 1.0000x reference)
//
#include <hip/hip_runtime.h>
#include <hip/hip_bf16.h>

typedef unsigned short u16;
typedef unsigned int u32;
typedef float f32x4 __attribute__((ext_vector_type(4)));
typedef int i32x4 __attribute__((ext_vector_type(4)));
typedef int i32x8 __attribute__((ext_vector_type(8)));

#define N_ROWS 8192
#define DIM 512
#define BM 128
#define BN 128
#define NREP 8             // accumulator replicas
// sqrt(1/0.07): folded into stored fp8 so MFMA emits sim/T directly
#define SCALE 3.77964473f
#define SCL1 0x7F7F7F7F    // e8m0 exponent 127 = x1.0 in all 4 scale bytes

// ------- kernel 1: L2-normalize rows -> fp8 e4m3 (pre-scaled); zero accs ---
__global__ __launch_bounds__(256) void norm_cast_kernel(
        const float* __restrict__ x, u32* __restrict__ hb8,
        float* __restrict__ accR /* 2*NREP*N_ROWS floats */,
        float* __restrict__ out) {
    int gid = blockIdx.x * 256 + threadIdx.x;
    if (gid < 2 * NREP * N_ROWS) accR[gid] = 0.f;
    if (gid == 0) out[0] = 0.f;
    int row  = blockIdx.x * 4 + (threadIdx.x >> 6);
    int lane = threadIdx.x & 63;
    const float4* xr = (const float4*)(x + (size_t)row * DIM);
    float4 v0 = xr[lane * 2 + 0];
    float4 v1 = xr[lane * 2 + 1];
    float ss = v0.x * v0.x + v0.y * v0.y + v0.z * v0.z + v0.w * v0.w
             + v1.x * v1.x + v1.y * v1.y + v1.z * v1.z + v1.w * v1.w;
#pragma unroll
    for (int off = 32; off; off >>= 1) ss += __shfl_xor(ss, off);
    float s = SCALE / fmaxf(sqrtf(ss), 1e-12f);
    // pack 8 fp8 (OCP e4m3 on gfx950, RNE+sat in HW)
    int w0 = __builtin_amdgcn_cvt_pk_fp8_f32(v0.x * s, v0.y * s, 0, false);
    w0     = __builtin_amdgcn_cvt_pk_fp8_f32(v0.z * s, v0.w * s, w0, true);
    int w1 = __builtin_amdgcn_cvt_pk_fp8_f32(v1.x * s, v1.y * s, 0, false);
    w1     = __builtin_amdgcn_cvt_pk_fp8_f32(v1.z * s, v1.w * s, w1, true);
    uint2 o; o.x = (u32)w0; o.y = (u32)w1;
    ((uint2*)((char*)hb8 + (size_t)row * DIM + lane * 8))[0] = o;
}

// stage helper: immediate offset must be a constant-expression for
// __builtin_amdgcn_global_load_lds -> template parameter.
template <int K0OFF>
__device__ __forceinline__ void stage_tiles(
        const char* const* gA, const char* const* gB,
        char* ldsA, char* ldsB, int tid) {
#pragma unroll
    for (int s2 = 0; s2 < 4; ++s2) {
        int seg = tid + s2 * 256;
        __builtin_amdgcn_global_load_lds(
            (const __attribute__((address_space(1))) void*)gA[s2],
            (__attribute__((address_space(3))) void*)&ldsA[seg * 16],
            16, K0OFF, 0);
        __builtin_amdgcn_global_load_lds(
            (const __attribute__((address_space(1))) void*)gB[s2],
            (__attribute__((address_space(3))) void*)&ldsB[seg * 16],
            16, K0OFF, 0);
    }
}

// ------- kernel 2: triangular fused tile GEMM (MX fp8 K=128) + sums --------
// R8 pair schedule + R10 fp8/BK=128 staging unchanged (proven: FETCH 13 MB,
// balance 8-9 tiles/CU). New: mfma_scale_f32_16x16x128_f8f6f4 with scale=1.0
// == four chained 16x16x32_fp8_fp8 but at the 2x MX rate, one call per
// 128-B slab. A-frag = 32 contiguous k-bytes/lane -> 2x ds_read_b128 (LDS
// instr count halves; 8-req/bank at distinct rows = data-limited).
// C/D layout identical to 16x16x32 (shape-determined) -> epilogue unchanged.
__global__ __launch_bounds__(256) void tile_kernel(
        const char* __restrict__ hb8, const int* __restrict__ labels,
        float* __restrict__ rowTotalR, float* __restrict__ rowPosR) {
    __shared__ __align__(16) char ldsA[BM * 128];   // 16 KB (one K=128 slab)
    __shared__ __align__(16) char ldsB[BN * 128];   // 16 KB
    __shared__ int labR[BM];
    __shared__ int labC[BN];
    __shared__ float cT[2][BN], cP[2][BN];
    __shared__ float rT[2][BM], rP[2][BM];

    const int b = blockIdx.x;
    const int c = b & 255;          // CU slot (round-robin)
    const int m = b >> 8;           // step 0..8
    const int y = c >> 3;
    const int p = 4 * (c & 7) + (y & 3);    // pair id [0,32)
    const int j = y >> 2;                   // CU within pair [0,8)
    const int t = j + 8 * m;                // tile index within pair
    if (t >= 65) return;
    int ti, tj;
    if (t <= p) { tj = p; ti = t; }
    else        { tj = 63 - p; ti = t - p - 1; }

    const int rowBase = ti * BM;
    const int colBase = tj * BN;
    const bool isDiag = (ti == tj);
    const int dd = colBase - rowBase;
    const int rep = (ti + tj) & (NREP - 1);
    const int tid = threadIdx.x;

    if (tid < 128) labR[tid] = labels[rowBase + tid];
    else           labC[tid - 128] = labels[colBase + tid - 128];

    const int w = tid >> 6;
    const int lane = tid & 63;
    const int wm = (w >> 1) * 64;
    const int wn = (w & 1) * 64;
    const int wr = w >> 1;
    const int wc = w & 1;
    const int quad = lane >> 4;
    const int l16 = lane & 15;

    // staging bases (computed once; k0 advances via immediate offset)
    const char* gA[4]; const char* gB[4];
#pragma unroll
    for (int s2 = 0; s2 < 4; ++s2) {
        int seg = tid + s2 * 256;         // 0..1023
        int r = seg >> 3;                 // 0..127
        int sl = seg & 7;                 // LDS 16-B slot
        int g = sl ^ (r & 7);             // global 16-B chunk within 128-B slab
        gA[s2] = hb8 + (size_t)(rowBase + r) * DIM + g * 16;
        gB[s2] = hb8 + (size_t)(colBase + r) * DIM + g * 16;
    }

    f32x4 acc[4][4];
#pragma unroll
    for (int i = 0; i < 4; ++i)
#pragma unroll
        for (int jj = 0; jj < 4; ++jj)
            acc[i][jj] = (f32x4){0.f, 0.f, 0.f, 0.f};

#pragma unroll
    for (int k0 = 0; k0 < 4; ++k0) {      // one K=128 slab per iteration
        switch (k0) {
            case 0: stage_tiles<0>(gA, gB, ldsA, ldsB, tid); break;
            case 1: stage_tiles<128>(gA, gB, ldsA, ldsB, tid); break;
            case 2: stage_tiles<256>(gA, gB, ldsA, ldsB, tid); break;
            default: stage_tiles<384>(gA, gB, ldsA, ldsB, tid); break;
        }
        __syncthreads();                  // drain + barrier

        // A/B fragments: lane (quad,l16) needs k-bytes quad*32..quad*32+31
        // of its row -> slab slots quad*2, quad*2+1 (xor-swizzled by row&7).
        i32x8 af[4], bfr[4];
#pragma unroll
        for (int im = 0; im < 4; ++im) {
            int row = wm + im * 16 + l16;
            int sl0 = (quad * 2 + 0) ^ (row & 7);
            int sl1 = (quad * 2 + 1) ^ (row & 7);
            i32x4 lo = *(const i32x4*)&ldsA[row * 128 + sl0 * 16];
            i32x4 hi = *(const i32x4*)&ldsA[row * 128 + sl1 * 16];
            af[im] = (i32x8){lo.x, lo.y, lo.z, lo.w, hi.x, hi.y, hi.z, hi.w};
        }
#pragma unroll
        for (int in = 0; in < 4; ++in) {
            int col = wn + in * 16 + l16;
            int sl0 = (quad * 2 + 0) ^ (col & 7);
            int sl1 = (quad * 2 + 1) ^ (col & 7);
            i32x4 lo = *(const i32x4*)&ldsB[col * 128 + sl0 * 16];
            i32x4 hi = *(const i32x4*)&ldsB[col * 128 + sl1 * 16];
            bfr[in] = (i32x8){lo.x, lo.y, lo.z, lo.w, hi.x, hi.y, hi.z, hi.w};
        }
#pragma unroll
        for (int im = 0; im < 4; ++im)
#pragma unroll
            for (int in = 0; in < 4; ++in)
                acc[im][in] = __builtin_amdgcn_mfma_scale_f32_16x16x128_f8f6f4(
                    af[im], bfr[in], acc[im][in],
                    0 /*cbsz: A=fp8 e4m3*/, 0 /*blgp: B=fp8 e4m3*/,
                    0, SCL1, 0, SCL1);
        __syncthreads();                  // protect buffers before next stage
    }

    // ---------------- epilogue (acc already = sim/T) ----------------
    // C/D layout: col = l16, row = quad*4 + reg (same as 16x16x32)
    int lc[4];
#pragma unroll
    for (int in = 0; in < 4; ++in) lc[in] = labC[wn + in * 16 + l16];

    float colT[4] = {0.f, 0.f, 0.f, 0.f}, colP[4] = {0.f, 0.f, 0.f, 0.f};
#pragma unroll
    for (int im = 0; im < 4; ++im) {
        float rowT[4] = {0.f, 0.f, 0.f, 0.f}, rowP[4] = {0.f, 0.f, 0.f, 0.f};
#pragma unroll
        for (int reg = 0; reg < 4; ++reg) {
            int rloc = wm + im * 16 + quad * 4 + reg;
            int li = labR[rloc];
#pragma unroll
            for (int in = 0; in < 4; ++in) {
                int cloc = wn + in * 16 + l16;
                float e = __expf(acc[im][in][reg]);
                bool pos = (lc[in] == li) && (rloc - cloc != dd);
                colT[in] += e; rowT[reg] += e;
                if (pos) { colP[in] += e; rowP[reg] += e; }
            }
        }
        if (!isDiag) {
#pragma unroll
            for (int reg = 0; reg < 4; ++reg) {
                float tt = rowT[reg], pp = rowP[reg];
                tt += __shfl_xor(tt, 1); tt += __shfl_xor(tt, 2);
                tt += __shfl_xor(tt, 4); tt += __shfl_xor(tt, 8);
                pp += __shfl_xor(pp, 1); pp += __shfl_xor(pp, 2);
                pp += __shfl_xor(pp, 4); pp += __shfl_xor(pp, 8);
                if (l16 == 0) {
                    int rloc = wm + im * 16 + quad * 4 + reg;
                    rT[wc][rloc] = tt;
                    rP[wc][rloc] = pp;
                }
            }
        }
    }
#pragma unroll
    for (int in = 0; in < 4; ++in) {
        float tt = colT[in], pp = colP[in];
        tt += __shfl_xor(tt, 16); tt += __shfl_xor(tt, 32);
        pp += __shfl_xor(pp, 16); pp += __shfl_xor(pp, 32);
        if (quad == 0) {
            int cloc = wn + in * 16 + l16;
            cT[wr][cloc] = tt;
            cP[wr][cloc] = pp;
        }
    }
    __syncthreads();
    float* rowTotal = rowTotalR + rep * N_ROWS;
    float* rowPos   = rowPosR   + rep * N_ROWS;
    if (tid < 128) {
        atomicAdd(&rowTotal[colBase + tid], cT[0][tid] + cT[1][tid]);
        if (!isDiag) atomicAdd(&rowTotal[rowBase + tid], rT[0][tid] + rT[1][tid]);
    } else {
        int t2 = tid - 128;
        atomicAdd(&rowPos[colBase + t2], cP[0][t2] + cP[1][t2]);
        if (!isDiag) atomicAdd(&rowPos[rowBase + t2], rP[0][t2] + rP[1][t2]);
    }
}

// ------- kernel 3: fold replicas + histogram + loss (64 blocks) ------------
__global__ __launch_bounds__(256) void reduce_loss_kernel(
        const int* __restrict__ labels, const float* __restrict__ rowTotalR,
        const float* __restrict__ rowPosR, float* __restrict__ out) {
    __shared__ int hist[128];
    __shared__ float red[256];
    int tid = threadIdx.x;
    if (tid < 128) hist[tid] = 0;
    __syncthreads();
    for (int i = tid; i < N_ROWS; i += 256)
        atomicAdd(&hist[labels[i] & 127], 1);
    __syncthreads();
    float sacc = 0.f;
    if (tid < 128) {
        int row = blockIdx.x * 128 + tid;
        float T = 0.f, P = 0.f;
#pragma unroll
        for (int r = 0; r < NREP; ++r) {
            T += rowTotalR[r * N_ROWS + row];
            P += rowPosR[r * N_ROWS + row];
        }
        float cc = (float)(hist[labels[row] & 127] - 1);
        sacc = logf((P / (cc + 1e-9f)) / T);
    }
    red[tid] = sacc;
    __syncthreads();
    for (int st = 128; st; st >>= 1) {
        if (tid < st) red[tid] += red[tid + st];
        __syncthreads();
    }
    if (tid == 0) atomicAdd(out, -red[0] / (float)N_ROWS);
}

extern "C" void kernel_launch(void* const* d_in, const int* in_sizes, int n_in,
                              void* d_out, int out_size, void* d_ws, size_t ws_size,
                              hipStream_t stream) {
    const float* hidden = (const float*)d_in[0];
    const int* labels   = (const int*)d_in[1];
    float* out = (float*)d_out;

    char* ws = (char*)d_ws;
    char* hb8 = ws;                                          // 8192*512 = 4 MB
    float* rowTotalR = (float*)(ws + (size_t)N_ROWS * DIM);  // NREP*8192 f
    float* rowPosR   = rowTotalR + NREP * N_ROWS;            // NREP*8192 f

    norm_cast_kernel<<<N_ROWS / 4, 256, 0, stream>>>(hidden, (u32*)hb8, rowTotalR, out);
    tile_kernel<<<9 * 256, 256, 0, stream>>>(hb8, labels, rowTotalR, rowPosR);
    reduce_loss_kernel<<<64, 256, 0, stream>>>(labels, rowTotalR, rowPosR, out);
}

// Round 15
// 119.783 us; speedup vs baseline: 1.3719x; 1.3719x over previous
//
#include <hip/hip_runtime.h>
#include <hip/hip_bf16.h>

typedef unsigned short u16;
typedef unsigned int u32;
typedef float f32x4 __attribute__((ext_vector_type(4)));

#define N_ROWS 8192
#define DIM 512
#define BM 128
#define BN 128
#define NREP 8             // accumulator replicas
// sqrt(1/(0.07*ln2)): folded into stored fp8 so MFMA emits sim/(T*ln2);
// epilogue then needs only exp2 (v_exp_f32), no per-element multiply.
#define SCALE 4.53982211f

// ------- kernel 1: L2-normalize rows -> fp8 e4m3 (pre-scaled); zero accs ---
__global__ __launch_bounds__(256) void norm_cast_kernel(
        const float* __restrict__ x, u32* __restrict__ hb8,
        float* __restrict__ accR /* 2*NREP*N_ROWS floats */,
        float* __restrict__ out) {
    int gid = blockIdx.x * 256 + threadIdx.x;
    if (gid < 2 * NREP * N_ROWS) accR[gid] = 0.f;
    if (gid == 0) out[0] = 0.f;
    int row  = blockIdx.x * 4 + (threadIdx.x >> 6);
    int lane = threadIdx.x & 63;
    const float4* xr = (const float4*)(x + (size_t)row * DIM);
    float4 v0 = xr[lane * 2 + 0];
    float4 v1 = xr[lane * 2 + 1];
    float ss = v0.x * v0.x + v0.y * v0.y + v0.z * v0.z + v0.w * v0.w
             + v1.x * v1.x + v1.y * v1.y + v1.z * v1.z + v1.w * v1.w;
#pragma unroll
    for (int off = 32; off; off >>= 1) ss += __shfl_xor(ss, off);
    float s = SCALE / fmaxf(sqrtf(ss), 1e-12f);
    // pack 8 fp8 (OCP e4m3 on gfx950, RNE+sat in HW)
    int w0 = __builtin_amdgcn_cvt_pk_fp8_f32(v0.x * s, v0.y * s, 0, false);
    w0     = __builtin_amdgcn_cvt_pk_fp8_f32(v0.z * s, v0.w * s, w0, true);
    int w1 = __builtin_amdgcn_cvt_pk_fp8_f32(v1.x * s, v1.y * s, 0, false);
    w1     = __builtin_amdgcn_cvt_pk_fp8_f32(v1.z * s, v1.w * s, w1, true);
    uint2 o; o.x = (u32)w0; o.y = (u32)w1;
    ((uint2*)((char*)hb8 + (size_t)row * DIM + lane * 8))[0] = o;
}

// stage helper: immediate offset must be a constant-expression for
// __builtin_amdgcn_global_load_lds -> template parameter.
template <int K0OFF>
__device__ __forceinline__ void stage_tiles(
        const char* const* gA, const char* const* gB,
        char* ldsA, char* ldsB, int tid) {
#pragma unroll
    for (int s2 = 0; s2 < 4; ++s2) {
        int seg = tid + s2 * 256;
        __builtin_amdgcn_global_load_lds(
            (const __attribute__((address_space(1))) void*)gA[s2],
            (__attribute__((address_space(3))) void*)&ldsA[seg * 16],
            16, K0OFF, 0);
        __builtin_amdgcn_global_load_lds(
            (const __attribute__((address_space(1))) void*)gB[s2],
            (__attribute__((address_space(3))) void*)&ldsB[seg * 16],
            16, K0OFF, 0);
    }
}

// ------- kernel 2: triangular fused tile GEMM (fp8) + exp + sums -----------
// R8 pair schedule + R10 body/sync EXACTLY (proven 53.5 us; pipelined
// variants R12-R14 all failed — reverted for good). Changes vs R10:
//  (1) swizzle gains row bit 3: swz(r) = (r&7)^((r>>3)&1). With the 128-B row
//      stride = 0 mod bank cycle, lanes l16 / l16+8 previously hit identical
//      banks (4.26M conflict cyc). Now they land on adjacent slots -> exactly
//      2 lanes/slot = data-limited minimum (2-way is free, m136).
//  (2) epilogue uses exp2 (scale pre-folded) -> 64 fewer v_mul per lane/tile.
__global__ __launch_bounds__(256) void tile_kernel(
        const char* __restrict__ hb8, const int* __restrict__ labels,
        float* __restrict__ rowTotalR, float* __restrict__ rowPosR) {
    __shared__ __align__(16) char ldsA[BM * 128];   // 16 KB (one K=128 slab)
    __shared__ __align__(16) char ldsB[BN * 128];   // 16 KB
    __shared__ int labR[BM];
    __shared__ int labC[BN];
    __shared__ float cT[2][BN], cP[2][BN];
    __shared__ float rT[2][BM], rP[2][BM];

    const int b = blockIdx.x;
    const int c = b & 255;          // CU slot (round-robin)
    const int m = b >> 8;           // step 0..8
    const int y = c >> 3;
    const int p = 4 * (c & 7) + (y & 3);    // pair id [0,32)
    const int j = y >> 2;                   // CU within pair [0,8)
    const int t = j + 8 * m;                // tile index within pair
    if (t >= 65) return;
    int ti, tj;
    if (t <= p) { tj = p; ti = t; }
    else        { tj = 63 - p; ti = t - p - 1; }

    const int rowBase = ti * BM;
    const int colBase = tj * BN;
    const bool isDiag = (ti == tj);
    const int dd = colBase - rowBase;
    const int rep = (ti + tj) & (NREP - 1);
    const int tid = threadIdx.x;

    if (tid < 128) labR[tid] = labels[rowBase + tid];
    else           labC[tid - 128] = labels[colBase + tid - 128];

    const int w = tid >> 6;
    const int lane = tid & 63;
    const int wm = (w >> 1) * 64;
    const int wn = (w & 1) * 64;
    const int wr = w >> 1;
    const int wc = w & 1;
    const int quad = lane >> 4;
    const int l16 = lane & 15;

    // staging bases (computed once; k0 advances via immediate offset)
    const char* gA[4]; const char* gB[4];
#pragma unroll
    for (int s2 = 0; s2 < 4; ++s2) {
        int seg = tid + s2 * 256;         // 0..1023
        int r = seg >> 3;                 // 0..127
        int sl = seg & 7;                 // LDS 16-B slot
        int g = sl ^ ((r & 7) ^ ((r >> 3) & 1));  // global chunk (swz bit 3)
        gA[s2] = hb8 + (size_t)(rowBase + r) * DIM + g * 16;
        gB[s2] = hb8 + (size_t)(colBase + r) * DIM + g * 16;
    }

    f32x4 acc[4][4];
#pragma unroll
    for (int i = 0; i < 4; ++i)
#pragma unroll
        for (int jj = 0; jj < 4; ++jj)
            acc[i][jj] = (f32x4){0.f, 0.f, 0.f, 0.f};

#pragma unroll
    for (int k0 = 0; k0 < 4; ++k0) {      // BK=128 bytes, imm offset k0*128
        switch (k0) {
            case 0: stage_tiles<0>(gA, gB, ldsA, ldsB, tid); break;
            case 1: stage_tiles<128>(gA, gB, ldsA, ldsB, tid); break;
            case 2: stage_tiles<256>(gA, gB, ldsA, ldsB, tid); break;
            default: stage_tiles<384>(gA, gB, ldsA, ldsB, tid); break;
        }
        __syncthreads();                  // drain + barrier (R10-proven)
#pragma unroll
        for (int kk = 0; kk < 4; ++kk) {  // four K=32 MFMA steps per slab
            long af[4], bfr[4];
#pragma unroll
            for (int im = 0; im < 4; ++im) {
                int row = wm + im * 16 + l16;
                int c4 = kk * 2 + (quad >> 1);
                int sl = c4 ^ ((row & 7) ^ ((row >> 3) & 1));
                af[im] = *(const long*)&ldsA[row * 128 + sl * 16 + (quad & 1) * 8];
            }
#pragma unroll
            for (int in = 0; in < 4; ++in) {
                int col = wn + in * 16 + l16;
                int c4 = kk * 2 + (quad >> 1);
                int sl = c4 ^ ((col & 7) ^ ((col >> 3) & 1));
                bfr[in] = *(const long*)&ldsB[col * 128 + sl * 16 + (quad & 1) * 8];
            }
#pragma unroll
            for (int im = 0; im < 4; ++im)
#pragma unroll
                for (int in = 0; in < 4; ++in)
                    acc[im][in] = __builtin_amdgcn_mfma_f32_16x16x32_fp8_fp8(
                        af[im], bfr[in], acc[im][in], 0, 0, 0);
        }
        __syncthreads();                  // protect buffers before next stage
    }

    // ---------------- epilogue (acc = sim/(T*ln2); e = exp2(acc)) ----------
    int lc[4];
#pragma unroll
    for (int in = 0; in < 4; ++in) lc[in] = labC[wn + in * 16 + l16];

    float colT[4] = {0.f, 0.f, 0.f, 0.f}, colP[4] = {0.f, 0.f, 0.f, 0.f};
#pragma unroll
    for (int im = 0; im < 4; ++im) {
        float rowT[4] = {0.f, 0.f, 0.f, 0.f}, rowP[4] = {0.f, 0.f, 0.f, 0.f};
#pragma unroll
        for (int reg = 0; reg < 4; ++reg) {
            int rloc = wm + im * 16 + quad * 4 + reg;
            int li = labR[rloc];
#pragma unroll
            for (int in = 0; in < 4; ++in) {
                int cloc = wn + in * 16 + l16;
                float e = __builtin_amdgcn_exp2f(acc[im][in][reg]);
                bool pos = (lc[in] == li) && (rloc - cloc != dd);
                colT[in] += e; rowT[reg] += e;
                if (pos) { colP[in] += e; rowP[reg] += e; }
            }
        }
        if (!isDiag) {
#pragma unroll
            for (int reg = 0; reg < 4; ++reg) {
                float tt = rowT[reg], pp = rowP[reg];
                tt += __shfl_xor(tt, 1); tt += __shfl_xor(tt, 2);
                tt += __shfl_xor(tt, 4); tt += __shfl_xor(tt, 8);
                pp += __shfl_xor(pp, 1); pp += __shfl_xor(pp, 2);
                pp += __shfl_xor(pp, 4); pp += __shfl_xor(pp, 8);
                if (l16 == 0) {
                    int rloc = wm + im * 16 + quad * 4 + reg;
                    rT[wc][rloc] = tt;
                    rP[wc][rloc] = pp;
                }
            }
        }
    }
#pragma unroll
    for (int in = 0; in < 4; ++in) {
        float tt = colT[in], pp = colP[in];
        tt += __shfl_xor(tt, 16); tt += __shfl_xor(tt, 32);
        pp += __shfl_xor(pp, 16); pp += __shfl_xor(pp, 32);
        if (quad == 0) {
            int cloc = wn + in * 16 + l16;
            cT[wr][cloc] = tt;
            cP[wr][cloc] = pp;
        }
    }
    __syncthreads();
    float* rowTotal = rowTotalR + rep * N_ROWS;
    float* rowPos   = rowPosR   + rep * N_ROWS;
    if (tid < 128) {
        atomicAdd(&rowTotal[colBase + tid], cT[0][tid] + cT[1][tid]);
        if (!isDiag) atomicAdd(&rowTotal[rowBase + tid], rT[0][tid] + rT[1][tid]);
    } else {
        int t2 = tid - 128;
        atomicAdd(&rowPos[colBase + t2], cP[0][t2] + cP[1][t2]);
        if (!isDiag) atomicAdd(&rowPos[rowBase + t2], rP[0][t2] + rP[1][t2]);
    }
}

// ------- kernel 3: fold replicas + histogram + loss (64 blocks) ------------
__global__ __launch_bounds__(256) void reduce_loss_kernel(
        const int* __restrict__ labels, const float* __restrict__ rowTotalR,
        const float* __restrict__ rowPosR, float* __restrict__ out) {
    __shared__ int hist[128];
    __shared__ float red[256];
    int tid = threadIdx.x;
    if (tid < 128) hist[tid] = 0;
    __syncthreads();
    for (int i = tid; i < N_ROWS; i += 256)
        atomicAdd(&hist[labels[i] & 127], 1);
    __syncthreads();
    float sacc = 0.f;
    if (tid < 128) {
        int row = blockIdx.x * 128 + tid;
        float T = 0.f, P = 0.f;
#pragma unroll
        for (int r = 0; r < NREP; ++r) {
            T += rowTotalR[r * N_ROWS + row];
            P += rowPosR[r * N_ROWS + row];
        }
        float cc = (float)(hist[labels[row] & 127] - 1);
        sacc = logf((P / (cc + 1e-9f)) / T);
    }
    red[tid] = sacc;
    __syncthreads();
    for (int st = 128; st; st >>= 1) {
        if (tid < st) red[tid] += red[tid + st];
        __syncthreads();
    }
    if (tid == 0) atomicAdd(out, -red[0] / (float)N_ROWS);
}

extern "C" void kernel_launch(void* const* d_in, const int* in_sizes, int n_in,
                              void* d_out, int out_size, void* d_ws, size_t ws_size,
                              hipStream_t stream) {
    const float* hidden = (const float*)d_in[0];
    const int* labels   = (const int*)d_in[1];
    float* out = (float*)d_out;

    char* ws = (char*)d_ws;
    char* hb8 = ws;                                          // 8192*512 = 4 MB
    float* rowTotalR = (float*)(ws + (size_t)N_ROWS * DIM);  // NREP*8192 f
    float* rowPosR   = rowTotalR + NREP * N_ROWS;            // NREP*8192 f

    norm_cast_kernel<<<N_ROWS / 4, 256, 0, stream>>>(hidden, (u32*)hb8, rowTotalR, out);
    tile_kernel<<<9 * 256, 256, 0, stream>>>(hb8, labels, rowTotalR, rowPosR);
    reduce_loss_kernel<<<64, 256, 0, stream>>>(labels, rowTotalR, rowPosR, out);
}